// Round 2
// baseline (2989.137 us; speedup 1.0000x reference)
//
#include <hip/hip_runtime.h>
#include <stdint.h>
#include <math.h>

// Problem dims (fixed by setup_inputs)
#define NB  16
#define NCI 128
#define NCO 256
#define NH  64
#define NWD 64

#define Y_ELEMS  (NB*NCO*NH*NWD)     // 16,777,216
#define Y_BYTES  (Y_ELEMS*4)         // 67,108,864

// workspace layout
#define NMAX_OFF 0                   // 256 x u64 = 2048 B
#define NBUF_OFF 2048                // 256 x f64 = 2048 B
#define RES_OFF  4096                // optional f32 residual buffer (Y_BYTES)

#define XTILE_R      20
#define XTILE_STRIDE 76              // 20x76 f32 = 6080 B LDS

struct Keys { uint32_t a[8]; uint32_t b[8]; };

// JAX threefry2x32 (20 rounds), bit-exact.
__host__ __device__ inline void threefry2x32(uint32_t k0, uint32_t k1,
                                             uint32_t x0, uint32_t x1,
                                             uint32_t* o0, uint32_t* o1)
{
  uint32_t ks2 = k0 ^ k1 ^ 0x1BD11BDAu;
  x0 += k0; x1 += k1;
#define TF_R(r) { x0 += x1; x1 = (x1 << (r)) | (x1 >> (32 - (r))); x1 ^= x0; }
  TF_R(13) TF_R(15) TF_R(26) TF_R(6)
  x0 += k1;  x1 += ks2 + 1u;
  TF_R(17) TF_R(29) TF_R(16) TF_R(24)
  x0 += ks2; x1 += k0 + 2u;
  TF_R(13) TF_R(15) TF_R(26) TF_R(6)
  x0 += k0;  x1 += k1 + 3u;
  TF_R(17) TF_R(29) TF_R(16) TF_R(24)
  x0 += k1;  x1 += ks2 + 4u;
  TF_R(13) TF_R(15) TF_R(26) TF_R(6)
  x0 += ks2; x1 += k0 + 5u;
#undef TF_R
  *o0 = x0; *o1 = x1;
}

// monotone double -> u64 key (order-preserving)
__device__ inline unsigned long long dkey(double d)
{
  unsigned long long b = (unsigned long long)__double_as_longlong(d);
  return (b & 0x8000000000000000ULL) ? ~b : (b | 0x8000000000000000ULL);
}

__global__ void init_kernel(unsigned long long* nmax)
{
  nmax[threadIdx.x] = 0ull;   // below every real-value key
}

// ---------------- conv: f64 accumulate, y -> d_out (b,c,h,w) f32 (+ residual), per-co max ----------------
// grid (NCO/8=32, NH/16=4, NB=16), block 256: wq=tid&15 -> w0=4*wq, hr=tid>>4 -> h=h0+hr
__global__ __launch_bounds__(256) void conv_kernel(const float* __restrict__ x,
                                                   const float* __restrict__ W,
                                                   float* __restrict__ y32,
                                                   float* __restrict__ yres, int use_res,
                                                   unsigned long long* __restrict__ nmax)
{
  __shared__ float tile[XTILE_R * XTILE_STRIDE];
  __shared__ double wred[4][8];

  const int co0 = blockIdx.x * 8;
  const int h0  = blockIdx.y * 16;
  const int b   = blockIdx.z;
  const int wq  = threadIdx.x & 15;
  const int hr  = threadIdx.x >> 4;
  const int w0  = wq * 4;
  const int h   = h0 + hr;

  double acc[4][8] = {};

  for (int ci = 0; ci < NCI; ++ci) {
    __syncthreads();  // protect tile from previous iteration's readers
    const float* xs = x + (size_t)(b * NCI + ci) * (NH * NWD);
    for (int idx = threadIdx.x; idx < XTILE_R * XTILE_STRIDE; idx += 256) {
      int r  = idx / XTILE_STRIDE;
      int cc = idx - r * XTILE_STRIDE;
      int gr = h0 - 2 + r;
      int gc = cc - 2;
      float v = 0.f;
      if ((unsigned)gr < 64u && (unsigned)gc < 64u) v = xs[gr * 64 + gc];
      tile[idx] = v;
    }
    __syncthreads();

    const float* wb = W + (size_t)co0 * (NCI * 25) + ci * 25;  // W[co][ci][kh][kw]
    #pragma unroll
    for (int kh = 0; kh < 5; ++kh) {
      const float* trow = &tile[(hr + kh) * XTILE_STRIDE + w0];
      float4 xa = *(const float4*)(trow);
      float4 xb = *(const float4*)(trow + 4);
      double xd[8] = { (double)xa.x, (double)xa.y, (double)xa.z, (double)xa.w,
                       (double)xb.x, (double)xb.y, (double)xb.z, (double)xb.w };
      #pragma unroll
      for (int j = 0; j < 8; ++j) {
        const float* wv = wb + (size_t)j * (NCI * 25) + kh * 5;  // block-uniform -> s_load
        double wd0 = (double)wv[0], wd1 = (double)wv[1], wd2 = (double)wv[2],
               wd3 = (double)wv[3], wd4 = (double)wv[4];
        #pragma unroll
        for (int px = 0; px < 4; ++px) {
          double s = acc[px][j];
          s = fma(xd[px + 0], wd0, s);
          s = fma(xd[px + 1], wd1, s);
          s = fma(xd[px + 2], wd2, s);
          s = fma(xd[px + 3], wd3, s);
          s = fma(xd[px + 4], wd4, s);
          acc[px][j] = s;
        }
      }
    }
  }

  // store y (f32 + optional residual) into (b,c,h,w) layout
  #pragma unroll
  for (int j = 0; j < 8; ++j) {
    float4 lo, rs;
    float* plo = (float*)&lo; float* prs = (float*)&rs;
    #pragma unroll
    for (int px = 0; px < 4; ++px) {
      float f = (float)acc[px][j];
      plo[px] = f;
      prs[px] = (float)(acc[px][j] - (double)f);
    }
    size_t addr = (((size_t)(b * NCO + co0 + j) * NH + h) * NWD + w0);
    *(float4*)(y32 + addr) = lo;
    if (use_res) *(float4*)(yres + addr) = rs;
  }

  // per-co exact max (f64) -> atomic
  double mx[8];
  #pragma unroll
  for (int j = 0; j < 8; ++j)
    mx[j] = fmax(fmax(acc[0][j], acc[1][j]), fmax(acc[2][j], acc[3][j]));
  #pragma unroll
  for (int j = 0; j < 8; ++j)
    for (int o = 32; o > 0; o >>= 1)
      mx[j] = fmax(mx[j], __shfl_xor(mx[j], o));

  if ((threadIdx.x & 63) == 0) {
    int wid = threadIdx.x >> 6;
    #pragma unroll
    for (int j = 0; j < 8; ++j) wred[wid][j] = mx[j];
  }
  __syncthreads();
  if (threadIdx.x < 8) {
    int j = threadIdx.x;
    double m = fmax(fmax(wred[0][j], wred[1][j]), fmax(wred[2][j], wred[3][j]));
    atomicMax(&nmax[co0 + j], dkey(m));
  }
}

// ---------------- n[c] = max + 1e-4 (f64) ----------------
__global__ void n_kernel(const unsigned long long* __restrict__ nmax,
                         double* __restrict__ nbuf)
{
  int c = threadIdx.x;
  unsigned long long u = nmax[c];
  unsigned long long bits = (u & 0x8000000000000000ULL) ? (u ^ 0x8000000000000000ULL) : ~u;
  double m = __longlong_as_double((long long)bits);
  nbuf[c] = m + 1e-4;
}

// ---------------- fused squash + dynamics, in-place on d_out ----------------
__device__ inline float4 blockMax4(float4 v)
{
  __shared__ float4 red[4];
  #pragma unroll
  for (int o = 32; o > 0; o >>= 1) {
    v.x = fmaxf(v.x, __shfl_xor(v.x, o));
    v.y = fmaxf(v.y, __shfl_xor(v.y, o));
    v.z = fmaxf(v.z, __shfl_xor(v.z, o));
    v.w = fmaxf(v.w, __shfl_xor(v.w, o));
  }
  __syncthreads();
  if ((threadIdx.x & 63) == 0) red[threadIdx.x >> 6] = v;
  __syncthreads();
  float4 a = red[0], b = red[1], c = red[2], d = red[3];
  float4 r;
  r.x = fmaxf(fmaxf(a.x, b.x), fmaxf(c.x, d.x));
  r.y = fmaxf(fmaxf(a.y, b.y), fmaxf(c.y, d.y));
  r.z = fmaxf(fmaxf(a.z, b.z), fmaxf(c.z, d.z));
  r.w = fmaxf(fmaxf(a.w, b.w), fmaxf(c.w, d.w));
  return r;
}

// grid 16384 blocks x 256 threads; block = 4 consecutive w-pixels, thread = channel
__global__ __launch_bounds__(256) void dyn_kernel(float* __restrict__ yio,
                                                  const float* __restrict__ yres, int use_res,
                                                  const double* __restrict__ nbuf,
                                                  Keys K, double tau)
{
  const int c   = threadIdx.x;
  const int g   = blockIdx.x;
  const int b   = g >> 10;
  const int hw0 = (g & 1023) * 4;

  const size_t addr = (size_t)(b * NCO + c) * 4096 + hw0;
  float4 yl = *(const float4*)(yio + addr);
  float4 yr = use_res ? *(const float4*)(yres + addr) : make_float4(0, 0, 0, 0);
  const float* pyl = (const float*)&yl;
  const float* pyr = (const float*)&yr;

  const double n = nbuf[c];
  const double inv8n = 8.0 / n;
  const double n04   = 0.4 * n;

  // squash in f64: y = n / (1 + exp(-(max(y,0) - 0.4n) * (8/n)))
  double y[4];
  #pragma unroll
  for (int p = 0; p < 4; ++p) {
    double yraw = (double)pyl[p] + (double)pyr[p];
    double yc = yraw > 0.0 ? yraw : 0.0;
    y[p] = n / (1.0 + exp(-((yc - n04) * inv8n)));
  }

  const uint32_t e0 = (uint32_t)((b * NCO + c) * 4096 + hw0);

  double mem[4] = {0.0, 0.0, 0.0, 0.0};
  float  xs[4]  = {0.f, 0.f, 0.f, 0.f};

  #pragma unroll
  for (int t = 0; t < 8; ++t) {
    double m[4]; bool sp[4];
    float4 pos;
    float* ppos = (float*)&pos;
    #pragma unroll
    for (int p = 0; p < 4; ++p) {
      m[p]  = mem[p] * tau + y[p];
      sp[p] = (m[p] - n) > 0.0;
      uint32_t o0, o1;
      threefry2x32(K.a[t], K.b[t], 0u, e0 + (uint32_t)p, &o0, &o1);
      uint32_t ub = ((o0 ^ o1) >> 9) | 0x3f800000u;
      float r = __uint_as_float(ub) - 1.0f;
      ppos[p] = sp[p] ? r : 0.f;
    }
    float4 pmax = blockMax4(pos);
    const float* ppm = (const float*)&pmax;

    float4 s2;
    float* ps2 = (float*)&s2;
    #pragma unroll
    for (int p = 0; p < 4; ++p)
      ps2[p] = (sp[p] && ppos[p] >= ppm[p]) ? 1.f : 0.f;

    float4 sm = blockMax4(s2);
    const float* psm = (const float*)&sm;

    #pragma unroll
    for (int p = 0; p < 4; ++p) {
      double m2 = sp[p] ? 0.0 : m[p];
      mem[p] = m2 - n * (double)psm[p];
      xs[p] += ps2[p];
    }
  }

  float4 o = make_float4(xs[0], xs[1], xs[2], xs[3]);
  *(float4*)(yio + addr) = o;
}

extern "C" void kernel_launch(void* const* d_in, const int* in_sizes, int n_in,
                              void* d_out, int out_size, void* d_ws, size_t ws_size,
                              hipStream_t stream)
{
  const float* x = (const float*)d_in[0];
  const float* W = (const float*)d_in[1];
  // T = 8 (fixed by setup_inputs)

  char* ws = (char*)d_ws;
  unsigned long long* nmax = (unsigned long long*)(ws + NMAX_OFF);
  double*             nbuf = (double*)(ws + NBUF_OFF);
  float*              yres = (float*)(ws + RES_OFF);
  const int use_res = (ws_size >= (size_t)RES_OFF + (size_t)Y_BYTES) ? 1 : 0;

  float* y = (float*)d_out;

  init_kernel<<<1, 256, 0, stream>>>(nmax);

  dim3 cgrid(NCO / 8, NH / 16, NB);
  conv_kernel<<<cgrid, 256, 0, stream>>>(x, W, y, yres, use_res, nmax);

  n_kernel<<<1, 256, 0, stream>>>(nmax, nbuf);

  // keys: partitionable foldlike split -> key_t = threefry(key, (0, t)), both words
  Keys K;
  for (int t = 0; t < 8; ++t) {
    uint32_t a, b;
    threefry2x32(0u, 42u, 0u, (uint32_t)t, &a, &b);
    K.a[t] = a; K.b[t] = b;
  }
  double tau = exp(-0.01);  // f64 TAU, matches Python float(np.exp(-1/100))

  dyn_kernel<<<NB * NH * NWD / 4, 256, 0, stream>>>(y, yres, use_res, nbuf, K, tau);
}